// Round 7
// baseline (274.998 us; speedup 1.0000x reference)
//
#include <hip/hip_runtime.h>
#include <hip/hip_bf16.h>

#define NN 16384
#define EE 128

typedef __attribute__((ext_vector_type(8))) short bf16x8;   // 8 bf16 = 4 VGPRs (MFMA A/B frag)
typedef __attribute__((ext_vector_type(4))) float f32x4;    // MFMA C/D frag
typedef __attribute__((ext_vector_type(4))) float f4;

static __device__ inline short f2bf(float f) {
    __hip_bfloat16 h = __float2bfloat16(f);
    return *reinterpret_cast<short*>(&h);
}

// ---------------------------------------------------------------------------
// pack_a: A [16384][128] fp32 -> Apk fragment-packed bf16 (mfma operand layout:
// lane&15 -> index, (lane>>4)*8+j -> k; feedable to either mfma slot).
// ---------------------------------------------------------------------------
__global__ __launch_bounds__(256) void pack_a(const float* __restrict__ A,
                                              bf16x8* __restrict__ out) {
    int lane = threadIdx.x & 63;
    int unit = blockIdx.x * 4 + (threadIdx.x >> 6);   // 0..4095
    int m16 = unit >> 2, ks = unit & 3;
    int row = m16 * 16 + (lane & 15);
    int k0  = ks * 32 + (lane >> 4) * 8;
    const float* src = A + (size_t)row * EE + k0;
    f4 v0 = *reinterpret_cast<const f4*>(src);
    f4 v1 = *reinterpret_cast<const f4*>(src + 4);
    bf16x8 r;
    r[0] = f2bf(v0[0]); r[1] = f2bf(v0[1]); r[2] = f2bf(v0[2]); r[3] = f2bf(v0[3]);
    r[4] = f2bf(v1[0]); r[5] = f2bf(v1[1]); r[6] = f2bf(v1[2]); r[7] = f2bf(v1[3]);
    out[(size_t)unit * 64 + lane] = r;
}

// ---------------------------------------------------------------------------
// pack_b: B [128][16384] fp32, W[128] -> Bpk = bf16(W[k]*B[k][n]), same layout.
// ---------------------------------------------------------------------------
__global__ __launch_bounds__(256) void pack_b(const float* __restrict__ B,
                                              const float* __restrict__ W,
                                              bf16x8* __restrict__ out) {
    int lane = threadIdx.x & 63;
    int unit = blockIdx.x * 4 + (threadIdx.x >> 6);   // 0..4095
    int n16 = unit >> 2, ks = unit & 3;
    int n  = n16 * 16 + (lane & 15);
    int k0 = ks * 32 + (lane >> 4) * 8;
    bf16x8 r;
#pragma unroll
    for (int j = 0; j < 8; ++j) {
        int k = k0 + j;
        r[j] = f2bf(W[k] * B[(size_t)k * NN + n]);
    }
    out[(size_t)unit * 64 + lane] = r;
}

// ---------------------------------------------------------------------------
// gemm_pk: identical to R6 (swapped-operand MFMA, all-b128 chunked-LDS
// epilogue, R3 bm-fast supertile walk, occupancy 4) with ONE change:
// C stores are NONTEMPORAL f4 (streaming, no L2 allocate). Theory: the 1 GB
// C write stream was thrashing the 4 MB per-XCD L2 that holds the operand
// panels (8 MB dirty per supertile pass vs 4 MB L2); nt stores take the
// write stream out of L2 so operand fetches stop contending with evictions.
// ---------------------------------------------------------------------------
__global__ __launch_bounds__(256, 4) void gemm_pk(const bf16x8* __restrict__ Apk,
                                                  const bf16x8* __restrict__ Bpk,
                                                  float* __restrict__ C) {
    // R3 walk: XCD chunking + bm-fast supertile (best measured baseline).
    int bid = blockIdx.x;
    int swz = (bid & 7) * 2048 + (bid >> 3);
    int st  = swz >> 11;            // supertile 0..7 (4 rows x 2 cols)
    int r   = swz & 2047;
    int bm  = (st >> 1) * 32 + (r & 31);
    int bn  = (st & 1) * 64 + (r >> 5);

    int lane = threadIdx.x & 63;
    int wid  = threadIdx.x >> 6;
    int wr   = wid >> 1, wc = wid & 1;
    int m16_0 = bm * 8 + wr * 4;
    int n16_0 = bn * 8 + wc * 4;

    f32x4 acc[4][4];
#pragma unroll
    for (int m = 0; m < 4; ++m)
#pragma unroll
        for (int n = 0; n < 4; ++n)
            acc[m][n] = (f32x4){0.f, 0.f, 0.f, 0.f};

#pragma unroll
    for (int ks = 0; ks < 4; ++ks) {
        bf16x8 a[4], b[4];
#pragma unroll
        for (int m = 0; m < 4; ++m)
            a[m] = Apk[(size_t)((m16_0 + m) * 4 + ks) * 64 + lane];
#pragma unroll
        for (int n = 0; n < 4; ++n)
            b[n] = Bpk[(size_t)((n16_0 + n) * 4 + ks) * 64 + lane];
#pragma unroll
        for (int m = 0; m < 4; ++m)
#pragma unroll
            for (int n = 0; n < 4; ++n)  // swapped operands (R4-verified math)
                acc[m][n] = __builtin_amdgcn_mfma_f32_16x16x32_bf16(b[n], a[m], acc[m][n], 0, 0, 0);
    }

    // ---- epilogue: chunked transpose, all-b128 LDS ops (R6) ----
    __shared__ float cst[4 * 16 * 64];          // 16 KB total, 4 KB per wave
    float* wl = cst + wid * (16 * 64);

    int rg  = lane >> 4;                         // lane group 0..3
    int l15 = lane & 15;
    int gr0 = bm * 128 + wr * 64;
    int gc0 = bn * 128 + wc * 64;

#pragma unroll
    for (int m = 0; m < 4; ++m) {
        // write: thread's f4 = row l15, cols n*16+rg*4+{0..3}  -> ds_write_b128
        int swW = (l15 & 7) << 2;
#pragma unroll
        for (int n = 0; n < 4; ++n) {
            int colf = (n * 16 + rg * 4) ^ swW;
            *reinterpret_cast<f4*>(&wl[l15 * 64 + colf]) = acc[m][n];
        }
        // read back: 4 rows x 256 B per instr -> ds_read_b128, then NT f4 store
#pragma unroll
        for (int r4 = 0; r4 < 4; ++r4) {
            int rl   = r4 * 4 + rg;
            int colf = (l15 * 4) ^ ((rl & 7) << 2);
            f4 v = *reinterpret_cast<const f4*>(&wl[rl * 64 + colf]);
            __builtin_nontemporal_store(v,
                reinterpret_cast<f4*>(&C[(size_t)(gr0 + m * 16 + rl) * NN + gc0 + l15 * 4]));
        }
        // next m reuses the same 4 KB chunk; wave-private -> no barrier.
    }
}

// ---------------------------------------------------------------------------
// Fallback (only if ws_size < 8 MB): plain fp32, correct but slow.
// ---------------------------------------------------------------------------
__global__ __launch_bounds__(64) void gemm_fb(const float* __restrict__ A,
                                              const float* __restrict__ B,
                                              const float* __restrict__ W,
                                              float* __restrict__ C) {
    int col = blockIdx.x * 64 + threadIdx.x;
    int row = blockIdx.y;
    float s = 0.f;
#pragma unroll 8
    for (int k = 0; k < EE; ++k)
        s = fmaf(A[(size_t)row * EE + k] * W[k], B[(size_t)k * NN + col], s);
    C[(size_t)row * NN + col] = s;
}

extern "C" void kernel_launch(void* const* d_in, const int* in_sizes, int n_in,
                              void* d_out, int out_size, void* d_ws, size_t ws_size,
                              hipStream_t stream) {
    const float* A = (const float*)d_in[0];   // DV2_H        [16384,128]
    const float* B = (const float*)d_in[1];   // invDE_HT_DV2 [128,16384]
    const float* W = (const float*)d_in[2];   // W            [128]
    float* C = (float*)d_out;                 // G            [16384,16384] fp32

    const size_t need = (size_t)2 * 4096 * 64 * sizeof(bf16x8);  // 8 MB
    if (ws_size >= need) {
        bf16x8* Apk = (bf16x8*)d_ws;
        bf16x8* Bpk = Apk + (size_t)4096 * 64;
        pack_a<<<1024, 256, 0, stream>>>(A, Apk);
        pack_b<<<1024, 256, 0, stream>>>(B, W, Bpk);
        gemm_pk<<<16384, 256, 0, stream>>>(Apk, Bpk, C);
    } else {
        dim3 g(NN / 64, NN);
        gemm_fb<<<g, 64, 0, stream>>>(A, B, W, C);
    }
}

// Round 8
// 248.445 us; speedup vs baseline: 1.1069x; 1.1069x over previous
//
#include <hip/hip_runtime.h>
#include <hip/hip_bf16.h>

#define NN 16384
#define EE 128

typedef __attribute__((ext_vector_type(8))) short bf16x8;   // 8 bf16 = 4 VGPRs (MFMA A/B frag)
typedef __attribute__((ext_vector_type(4))) float f32x4;    // MFMA C/D frag
typedef __attribute__((ext_vector_type(4))) float f4;

static __device__ inline short f2bf(float f) {
    __hip_bfloat16 h = __float2bfloat16(f);
    return *reinterpret_cast<short*>(&h);
}

// ---------------------------------------------------------------------------
// pack_a: A [16384][128] fp32 -> Apk fragment-packed bf16 (mfma operand layout:
// lane&15 -> index, (lane>>4)*8+j -> k; feedable to either mfma slot).
// ---------------------------------------------------------------------------
__global__ __launch_bounds__(256) void pack_a(const float* __restrict__ A,
                                              bf16x8* __restrict__ out) {
    int lane = threadIdx.x & 63;
    int unit = blockIdx.x * 4 + (threadIdx.x >> 6);   // 0..4095
    int m16 = unit >> 2, ks = unit & 3;
    int row = m16 * 16 + (lane & 15);
    int k0  = ks * 32 + (lane >> 4) * 8;
    const float* src = A + (size_t)row * EE + k0;
    f4 v0 = *reinterpret_cast<const f4*>(src);
    f4 v1 = *reinterpret_cast<const f4*>(src + 4);
    bf16x8 r;
    r[0] = f2bf(v0[0]); r[1] = f2bf(v0[1]); r[2] = f2bf(v0[2]); r[3] = f2bf(v0[3]);
    r[4] = f2bf(v1[0]); r[5] = f2bf(v1[1]); r[6] = f2bf(v1[2]); r[7] = f2bf(v1[3]);
    out[(size_t)unit * 64 + lane] = r;
}

// ---------------------------------------------------------------------------
// pack_b: B [128][16384] fp32, W[128] -> Bpk = bf16(W[k]*B[k][n]), same layout.
// ---------------------------------------------------------------------------
__global__ __launch_bounds__(256) void pack_b(const float* __restrict__ B,
                                              const float* __restrict__ W,
                                              bf16x8* __restrict__ out) {
    int lane = threadIdx.x & 63;
    int unit = blockIdx.x * 4 + (threadIdx.x >> 6);   // 0..4095
    int n16 = unit >> 2, ks = unit & 3;
    int n  = n16 * 16 + (lane & 15);
    int k0 = ks * 32 + (lane >> 4) * 8;
    bf16x8 r;
#pragma unroll
    for (int j = 0; j < 8; ++j) {
        int k = k0 + j;
        r[j] = f2bf(W[k] * B[(size_t)k * NN + n]);
    }
    out[(size_t)unit * 64 + lane] = r;
}

// ---------------------------------------------------------------------------
// gemm_pk: block tile 64x256 (4 waves side-by-side, each 64x64 via swapped-
// operand mfma). ONE structural change vs R6: block-cooperative epilogue --
// per 16-row m-band, all 4 waves stage into a shared 16x256 LDS buffer
// (XOR-swizzled, all ds_*_b128), barrier, then each wave stores whole
// 1 KB CONTIGUOUS rows of C (the fill-kernel store pattern; R6 emitted
// 4x256B scattered segments per wave-store). LDS op count unchanged.
// Plain (non-NT) stores -- NT regressed in R7.
// ---------------------------------------------------------------------------
__global__ __launch_bounds__(256, 4) void gemm_pk(const bf16x8* __restrict__ Apk,
                                                  const bf16x8* __restrict__ Bpk,
                                                  float* __restrict__ C) {
    // XCD chunking, bm-fast (R3/R6 best walk). bm in [0,256) (64-row tiles),
    // bn in [0,64) (256-col tiles). Per-XCD working set < 1 MB.
    int bid = blockIdx.x;
    int xcd = bid & 7;
    int r   = bid >> 3;                 // 0..2047
    int bm  = xcd * 32 + (r & 31);      // bm-fast
    int bn  = r >> 5;

    int lane = threadIdx.x & 63;
    int wid  = threadIdx.x >> 6;        // wave 0..3 = column quarter
    int m16_0 = bm * 4;                 // 4 m16-frags (64 rows)
    int n16_0 = bn * 16 + wid * 4;      // 4 n16-frags (64 cols of this wave)

    f32x4 acc[4][4];
#pragma unroll
    for (int m = 0; m < 4; ++m)
#pragma unroll
        for (int n = 0; n < 4; ++n)
            acc[m][n] = (f32x4){0.f, 0.f, 0.f, 0.f};

#pragma unroll
    for (int ks = 0; ks < 4; ++ks) {
        bf16x8 a[4], b[4];
#pragma unroll
        for (int m = 0; m < 4; ++m)
            a[m] = Apk[(size_t)((m16_0 + m) * 4 + ks) * 64 + lane];
#pragma unroll
        for (int n = 0; n < 4; ++n)
            b[n] = Bpk[(size_t)((n16_0 + n) * 4 + ks) * 64 + lane];
#pragma unroll
        for (int m = 0; m < 4; ++m)
#pragma unroll
            for (int n = 0; n < 4; ++n)  // swapped operands: thread owns a row-
                acc[m][n] = __builtin_amdgcn_mfma_f32_16x16x32_bf16(b[n], a[m], acc[m][n], 0, 0, 0);
    }
    // thread owns: C row bm*64 + m*16 + (lane&15),
    //              cols bn*256 + wid*64 + n*16 + (lane>>4)*4 + {0..3}

    // ---- epilogue: block-cooperative 16x256 m-band staging, 1KB row stores --
    __shared__ float sb[16 * 256];               // 16 KB
    int rg  = lane >> 4;                          // 0..3
    int l15 = lane & 15;
    size_t growb = (size_t)bm * 64;
    int    gcolb = bn * 256;

#pragma unroll
    for (int m = 0; m < 4; ++m) {
        // write: wave wid covers cols wid*64 + n*16 + rg*4, rows l15.
        // swizzle (16B-preserving): colf ^= (row&7)<<2  -> uniform banks.
        int swW = (l15 & 7) << 2;
#pragma unroll
        for (int n = 0; n < 4; ++n) {
            int colf = (wid * 64 + n * 16 + rg * 4) ^ swW;
            *reinterpret_cast<f4*>(&sb[l15 * 256 + colf]) = acc[m][n];
        }
        __syncthreads();
        // read+store: wave wid handles rows i*4+wid; 64 lanes x 16B = one
        // full 1 KB contiguous row per instruction.
#pragma unroll
        for (int i = 0; i < 4; ++i) {
            int rl   = i * 4 + wid;
            int colf = (lane * 4) ^ ((rl & 7) << 2);
            f4 v = *reinterpret_cast<const f4*>(&sb[rl * 256 + colf]);
            *reinterpret_cast<f4*>(
                &C[(growb + m * 16 + rl) * NN + gcolb + lane * 4]) = v;
        }
        __syncthreads();   // before next band overwrites sb
    }
}

// ---------------------------------------------------------------------------
// Fallback (only if ws_size < 8 MB): plain fp32, correct but slow.
// ---------------------------------------------------------------------------
__global__ __launch_bounds__(64) void gemm_fb(const float* __restrict__ A,
                                              const float* __restrict__ B,
                                              const float* __restrict__ W,
                                              float* __restrict__ C) {
    int col = blockIdx.x * 64 + threadIdx.x;
    int row = blockIdx.y;
    float s = 0.f;
#pragma unroll 8
    for (int k = 0; k < EE; ++k)
        s = fmaf(A[(size_t)row * EE + k] * W[k], B[(size_t)k * NN + col], s);
    C[(size_t)row * NN + col] = s;
}

extern "C" void kernel_launch(void* const* d_in, const int* in_sizes, int n_in,
                              void* d_out, int out_size, void* d_ws, size_t ws_size,
                              hipStream_t stream) {
    const float* A = (const float*)d_in[0];   // DV2_H        [16384,128]
    const float* B = (const float*)d_in[1];   // invDE_HT_DV2 [128,16384]
    const float* W = (const float*)d_in[2];   // W            [128]
    float* C = (float*)d_out;                 // G            [16384,16384] fp32

    const size_t need = (size_t)2 * 4096 * 64 * sizeof(bf16x8);  // 8 MB
    if (ws_size >= need) {
        bf16x8* Apk = (bf16x8*)d_ws;
        bf16x8* Bpk = Apk + (size_t)4096 * 64;
        pack_a<<<1024, 256, 0, stream>>>(A, Apk);
        pack_b<<<1024, 256, 0, stream>>>(B, W, Bpk);
        gemm_pk<<<16384, 256, 0, stream>>>(Apk, Bpk, C);
    } else {
        dim3 g(NN / 64, NN);
        gemm_fb<<<g, 64, 0, stream>>>(A, B, W, C);
    }
}